// Round 3
// baseline (366.603 us; speedup 1.0000x reference)
//
#include <hip/hip_runtime.h>

#define N_NODES  100000
#define N_EDGES  1600000
#define N_GRAPHS 256
#define F        64

#define CAST_ELEMS (N_NODES * F / 4)   // 1,600,000 float4

// ---------------------------------------------------------------------------
// R20 restructure. Evidence: total 183.7 us with gather_pool=80.3 -> old
// K1(prep, 196 blocks, serial LDS phases) + K2(compact, 8-step LDS binary
// search per edge) ~= 100 us for ~10 us of ideal traffic. K3 only needs
// per-node CONTIGUOUS runs in eidx, not globally sorted ones -> replace the
// whole sort with a 3-pass global-atomic counting sort (hist / alloc /
// scatter), all L2-resident. Also: R18/R19 proved K3 residency is capped
// ~11 waves/CU regardless of grid (occupancy 34% at both 4000 and 7693
// waves; dur 80.3 vs 89.7) -> revert NODES_PER_WAVE to 25 (less per-wave
// Wg-preload overhead), plain __launch_bounds__(256) (the (256,8) variant
// forced VGPR 32 and spilled: WRITE_SIZE 1.2->92.6 MB, 2.8x regression).
// ---------------------------------------------------------------------------

__device__ __forceinline__ unsigned short f2bf(float f) {
    unsigned int u = __float_as_uint(f);
    u += 0x7FFFu + ((u >> 16) & 1u);
    return (unsigned short)(u >> 16);
}

// ---------- K0: init + cast(x->bf16) ----------
__global__ __launch_bounds__(256) void init_cast_kernel(
        const float* __restrict__ x, unsigned short* __restrict__ xh,
        int* __restrict__ cnt, float* __restrict__ out,
        float* __restrict__ denom, unsigned int* __restrict__ allocp) {
    int gtid   = blockIdx.x * 256 + threadIdx.x;
    int stride = gridDim.x * 256;
    for (int i = gtid; i < CAST_ELEMS; i += stride) {
        float4 v = ((const float4*)x)[i];
        ushort4 o;
        o.x = f2bf(v.x); o.y = f2bf(v.y); o.z = f2bf(v.z); o.w = f2bf(v.w);
        ((ushort4*)xh)[i] = o;
    }
    for (int i = gtid; i < N_NODES; i += stride) cnt[i] = 0;
    if (gtid < N_GRAPHS * F) out[gtid] = 0.f;
    if (gtid < N_GRAPHS) denom[gtid] = 0.f;
    if (gtid == 0) *allocp = 0u;
}

// ---------- K1: per-node degree histogram (1.6M atomics, L2-resident) ----------
__global__ __launch_bounds__(256) void hist_kernel(
        const int* __restrict__ dst, int* __restrict__ cnt) {
    int gtid   = blockIdx.x * 256 + threadIdx.x;
    int stride = gridDim.x * 256;
    for (int e = gtid; e < N_EDGES; e += stride)
        atomicAdd(&cnt[dst[e]], 1);
}

// ---------- K2: run allocation. Node runs land in eidx in ARBITRARY order
// (one atomic per wave on a single allocator) — K3 only reads nbeg/nend. ----------
__global__ __launch_bounds__(256) void alloc_kernel(
        const int* __restrict__ cnt,
        int* __restrict__ nbeg, int* __restrict__ nend, int* __restrict__ cur,
        unsigned int* __restrict__ allocp) {
    int i    = blockIdx.x * 256 + threadIdx.x;
    int lane = threadIdx.x & 63;
    int c = (i < N_NODES) ? cnt[i] : 0;
    int v = c;
    #pragma unroll
    for (int o = 1; o < 64; o <<= 1) {
        int u = __shfl_up(v, o, 64);
        if (lane >= o) v += u;
    }
    int base = 0;
    if (lane == 63) base = (int)atomicAdd(allocp, (unsigned int)v);
    base = __shfl(base, 63, 64);
    if (i < N_NODES) {
        int b = base + v - c;
        nbeg[i] = b;
        nend[i] = b + c;
        cur[i]  = b;
    }
}

// ---------- K3s: edge scatter into per-node runs ----------
__global__ __launch_bounds__(256) void scatter_kernel(
        const int* __restrict__ src, const int* __restrict__ dst,
        int* __restrict__ cur, int* __restrict__ eidx) {
    int gtid   = blockIdx.x * 256 + threadIdx.x;
    int stride = gridDim.x * 256;
    for (int e = gtid; e < N_EDGES; e += stride) {
        int d = dst[e];
        int slot = atomicAdd(&cur[d], 1);
        eidx[slot] = src[e];
    }
}

// ---------- K3: fused gather(bf16)+transform+pool (R0-proven body) ----------
#define NODES_PER_WAVE 25
#define GT_NWAVES  (N_NODES / NODES_PER_WAVE)   // 4000
#define GT_BLOCKS  (GT_NWAVES / 4)              // 1000

__device__ __forceinline__ float bfl(unsigned int u) { return __uint_as_float(u << 16); }
__device__ __forceinline__ float bfh(unsigned int u) { return __uint_as_float(u & 0xFFFF0000u); }

__global__ __launch_bounds__(256) void gather_pool_kernel(
        const unsigned short* __restrict__ xh,
        const int*   __restrict__ nbeg,
        const int*   __restrict__ nend,
        const int*   __restrict__ eidx,
        const int*   __restrict__ batch,
        const float* __restrict__ Wg,   // [64,64] (k, f)
        const float* __restrict__ bg,
        const float* __restrict__ Wa,
        const float* __restrict__ ba,
        float*       __restrict__ out_acc,   // [N_GRAPHS, F]
        float*       __restrict__ denom) {  // [N_GRAPHS]
    int tid  = threadIdx.x;
    int lane = tid & 63;
    int grp  = lane >> 3;   // 0..7: row within an 8-row gather batch
    int c    = lane & 7;    // 16-B chunk (8 bf16) within a row
    int waveId = blockIdx.x * 4 + (tid >> 6);

    int n0   = waveId * NODES_PER_WAVE;     // grid exactly covers N_NODES
    int nEnd = n0 + NODES_PER_WAVE;

    float wcol[F];
    #pragma unroll
    for (int k = 0; k < F; ++k) wcol[k] = Wg[k * F + lane];
    float bgl = bg[lane];
    float wal = Wa[lane];
    float ba0 = ba[0];

    const uint4* xh4 = (const uint4*)xh;     // row = 8 uint4

    int   cur_g = batch[n0];
    float accw  = 0.f;   // per-lane: sum e * h[lane]
    float denw  = 0.f;   // replicated: sum e

    // prefetch state: first-chunk edge indices of the current node
    int pb = nbeg[n0];
    int pe = nend[n0];
    int sl_cur = (pb + lane < pe) ? eidx[pb + lane] : 0;

    for (int n = n0; n < nEnd; ++n) {
        int start = pb, end = pe;
        int sl    = sl_cur;
        if (n + 1 < nEnd) {     // prefetch node n+1 while n's gathers fly
            pb = nbeg[n + 1];
            pe = nend[n + 1];
            sl_cur = (pb + lane < pe) ? eidx[pb + lane] : 0;
        }

        float a0=0.f,a1=0.f,a2=0.f,a3=0.f,a4=0.f,a5=0.f,a6=0.f,a7=0.f;
        // first (almost always only) 64-edge chunk
        {
            int jmax = end - start; if (jmax > 64) jmax = 64;
            for (int j = 0; j < jmax; j += 8) {
                int el = j + grp;
                int s  = __shfl(sl, el, 64);
                if (el < jmax) {
                    uint4 v = xh4[s * 8 + c];   // 16 B/lane, 8 rows per instruction
                    a0 += bfl(v.x); a1 += bfh(v.x);
                    a2 += bfl(v.y); a3 += bfh(v.y);
                    a4 += bfl(v.z); a5 += bfh(v.z);
                    a6 += bfl(v.w); a7 += bfh(v.w);
                }
            }
        }
        // rare extra chunks (deg > 64)
        for (int base = start + 64; base < end; base += 64) {
            int jmax = end - base; if (jmax > 64) jmax = 64;
            int sl2 = (base + lane < end) ? eidx[base + lane] : 0;
            for (int j = 0; j < jmax; j += 8) {
                int el = j + grp;
                int s  = __shfl(sl2, el, 64);
                if (el < jmax) {
                    uint4 v = xh4[s * 8 + c];
                    a0 += bfl(v.x); a1 += bfh(v.x);
                    a2 += bfl(v.y); a3 += bfh(v.y);
                    a4 += bfl(v.z); a5 += bfh(v.z);
                    a6 += bfl(v.w); a7 += bfh(v.w);
                }
            }
        }
        #pragma unroll
        for (int o = 8; o <= 32; o <<= 1) {
            a0 += __shfl_xor(a0, o, 64); a1 += __shfl_xor(a1, o, 64);
            a2 += __shfl_xor(a2, o, 64); a3 += __shfl_xor(a3, o, 64);
            a4 += __shfl_xor(a4, o, 64); a5 += __shfl_xor(a5, o, 64);
            a6 += __shfl_xor(a6, o, 64); a7 += __shfl_xor(a7, o, 64);
        }
        {
            uint4 v = xh4[n * 8 + c];   // self row
            a0 += bfl(v.x); a1 += bfh(v.x);
            a2 += bfl(v.y); a3 += bfh(v.y);
            a4 += bfl(v.z); a5 += bfh(v.z);
            a6 += bfl(v.w); a7 += bfh(v.w);
        }

        float re[8] = {a0,a1,a2,a3,a4,a5,a6,a7};
        float q0=0.f,q1=0.f,q2=0.f,q3=0.f,q4=0.f,q5=0.f,q6=0.f,q7=0.f;
        #pragma unroll
        for (int k = 0; k < F; k += 8) {
            int ln = k >> 3;
            q0 += __int_as_float(__builtin_amdgcn_readlane(__float_as_int(re[0]), ln)) * wcol[k + 0];
            q1 += __int_as_float(__builtin_amdgcn_readlane(__float_as_int(re[1]), ln)) * wcol[k + 1];
            q2 += __int_as_float(__builtin_amdgcn_readlane(__float_as_int(re[2]), ln)) * wcol[k + 2];
            q3 += __int_as_float(__builtin_amdgcn_readlane(__float_as_int(re[3]), ln)) * wcol[k + 3];
            q4 += __int_as_float(__builtin_amdgcn_readlane(__float_as_int(re[4]), ln)) * wcol[k + 4];
            q5 += __int_as_float(__builtin_amdgcn_readlane(__float_as_int(re[5]), ln)) * wcol[k + 5];
            q6 += __int_as_float(__builtin_amdgcn_readlane(__float_as_int(re[6]), ln)) * wcol[k + 6];
            q7 += __int_as_float(__builtin_amdgcn_readlane(__float_as_int(re[7]), ln)) * wcol[k + 7];
        }
        float hv = ((q0 + q1) + (q2 + q3)) + ((q4 + q5) + (q6 + q7)) + bgl;
        hv = hv > 0.f ? hv : 0.f;

        float p = hv * wal;
        #pragma unroll
        for (int o = 32; o > 0; o >>= 1)
            p += __shfl_down(p, o, 64);
        float s = __int_as_float(__builtin_amdgcn_readlane(__float_as_int(p), 0)) + ba0;
        float e = __expf(s);    // unshifted: softmax ratio is shift-invariant

        int g = batch[n];       // wave-uniform
        if (g != cur_g) {
            atomicAdd(&out_acc[cur_g * F + lane], accw);
            if (lane == 0) atomicAdd(&denom[cur_g], denw);
            accw = 0.f; denw = 0.f; cur_g = g;
        }
        accw += e * hv;
        denw += e;
    }
    atomicAdd(&out_acc[cur_g * F + lane], accw);
    if (lane == 0) atomicAdd(&denom[cur_g], denw);
}

// ---------- K4: out /= denom ----------
__global__ __launch_bounds__(256) void finalize_kernel(
        float* __restrict__ out, const float* __restrict__ denom) {
    int i = blockIdx.x * 256 + threadIdx.x;
    if (i >= N_GRAPHS * F) return;
    float d = denom[i >> 6];
    out[i] = (d > 0.f) ? out[i] / d : 0.f;
}

extern "C" void kernel_launch(void* const* d_in, const int* in_sizes, int n_in,
                              void* d_out, int out_size, void* d_ws, size_t ws_size,
                              hipStream_t stream) {
    const float* x     = (const float*)d_in[0];
    const int*   ei    = (const int*)d_in[1];   // [2, N_EDGES]
    const int*   batch = (const int*)d_in[2];   // [N_NODES]
    const float* Wg    = (const float*)d_in[3];
    const float* bg    = (const float*)d_in[4];
    const float* Wa    = (const float*)d_in[5];
    const float* ba    = (const float*)d_in[6];
    float* out = (float*)d_out;

    const int* src = ei;
    const int* dst = ei + N_EDGES;

    // workspace layout (bytes, 256-aligned)
    char* ws = (char*)d_ws;
    unsigned short* xh    = (unsigned short*)(ws);             // 12,800,000
    int*            eidx  = (int*)(ws + 12800000);             //  6,400,000
    int*            cnt   = (int*)(ws + 19200000);             //    400,000
    int*            nbeg  = (int*)(ws + 19600000);             //    400,000
    int*            nend  = (int*)(ws + 20000000);             //    400,000
    int*            cur   = (int*)(ws + 20400000);             //    400,000
    float*          denom = (float*)(ws + 20800000);           //      1,024
    unsigned int*   allocp= (unsigned int*)(ws + 20801024);    //        256

    init_cast_kernel<<<2048, 256, 0, stream>>>(x, xh, cnt, out, denom, allocp);
    hist_kernel     <<<2048, 256, 0, stream>>>(dst, cnt);
    alloc_kernel    <<<(N_NODES + 255) / 256, 256, 0, stream>>>(cnt, nbeg, nend, cur, allocp);
    scatter_kernel  <<<2048, 256, 0, stream>>>(src, dst, cur, eidx);
    gather_pool_kernel <<<GT_BLOCKS, 256, 0, stream>>>(
        xh, nbeg, nend, eidx, batch, Wg, bg, Wa, ba, out, denom);
    finalize_kernel <<<(N_GRAPHS * F + 255) / 256, 256, 0, stream>>>(out, denom);
}

// Round 4
// 179.265 us; speedup vs baseline: 2.0450x; 2.0450x over previous
//
#include <hip/hip_runtime.h>

#define N_NODES  100000
#define N_EDGES  1600000
#define N_GRAPHS 256
#define F        64

// ---------------------------------------------------------------------------
// R21. Evidence chain:
//  - R0 pipeline: gather_pool=80.3us, prep+compact ~100us (total 183.7).
//  - R20 global-atomic scatter: 130us, WRITE_SIZE=107MB for 6.4MB payload ->
//    random 4B global writes cost a 64B line each (1.6M x 64B ~= 102MB). Any
//    design MUST stage writes in LDS and emit coalesced runs.
//  - R18/R19: K3 occupancy pinned ~34% regardless of grid size; (256,8)
//    launch bound spills (VGPR 60->32, +90MB scratch traffic). K3 stays at
//    NODES_PER_WAVE=25, plain __launch_bounds__(256).
// Design: pass1 bins edges into 391 bucket-contiguous regions (256 nodes
// each) via LDS sort + one global atomicAdd per (block,bucket) run + 84B-run
// coalesced writes. Pass2 reads each bucket CONTIGUOUSLY (kills the old
// 196-run binary-search compact), LDS counting-sorts by node, rewrites the
// same buffer in place as eidx. x->bf16 cast rides along as extra blocks.
// ---------------------------------------------------------------------------

#define CHUNK    8192
#define NCHUNK   196                     // ceil(N_EDGES / CHUNK)
#define NBUCK    391                     // ceil(N_NODES / 256), bucket = dst>>8
#define BCAP     5120                    // bucket cap: mean 4096, sigma 64 -> +16 sigma

#define CAST_ELEMS   (N_NODES * F / 4)   // 1,600,000 float4
#define CAST_BLOCKS  ((CAST_ELEMS + 1023) / 1024)   // 1563
#define BC_BLOCKS    (NCHUNK + CAST_BLOCKS)         // 1759

__device__ __forceinline__ unsigned short f2bf(float f) {
    unsigned int u = __float_as_uint(f);
    u += 0x7FFFu + ((u >> 16) & 1u);
    return (unsigned short)(u >> 16);
}

// ---------- K0: zero balloc / out / denom ----------
__global__ __launch_bounds__(256) void zero_kernel(
        int* __restrict__ balloc, float* __restrict__ out,
        float* __restrict__ denom) {
    int i = blockIdx.x * 256 + threadIdx.x;
    if (i < NBUCK) balloc[i] = 0;
    if (i < N_GRAPHS * F) out[i] = 0.f;
    if (i < N_GRAPHS) denom[i] = 0.f;
}

// ---------- K1: bucket binning (blocks [0,196)) + x->bf16 cast (rest) ----------
__global__ __launch_bounds__(1024) void bin_cast_kernel(
        const int* __restrict__ src, const int* __restrict__ dst,
        const float* __restrict__ x, unsigned short* __restrict__ xh,
        unsigned int* __restrict__ pairs, int* __restrict__ balloc) {
    int tid = threadIdx.x;
    int b   = blockIdx.x;

    if (b >= NCHUNK) {              // ---- streaming cast section ----
        int i = (b - NCHUNK) * 1024 + tid;
        if (i < CAST_ELEMS) {
            float4 v = ((const float4*)x)[i];
            ushort4 o;
            o.x = f2bf(v.x); o.y = f2bf(v.y); o.z = f2bf(v.z); o.w = f2bf(v.w);
            ((ushort4*)xh)[i] = o;
        }
        return;
    }

    // ---- bin section ----
    __shared__ int hist[NBUCK];
    __shared__ int roffs[NBUCK];
    __shared__ int curs[NBUCK];
    __shared__ int bbase[NBUCK];
    __shared__ int wsum[16];
    __shared__ unsigned int   stage[CHUNK];    // 32 KB
    __shared__ unsigned short bstage[CHUNK];   // 16 KB

    int base = b * CHUNK;
    int m    = min(CHUNK, N_EDGES - base);
    int lane = tid & 63;
    int wv   = tid >> 6;

    for (int k = tid; k < NBUCK; k += 1024) hist[k] = 0;
    __syncthreads();

    // load edges once into registers (compile-time indices - no scratch)
    int de[8], se[8];
    #pragma unroll
    for (int r = 0; r < 8; ++r) {
        int e = tid + r * 1024;
        if (e < m) {
            de[r] = dst[base + e];
            se[r] = src[base + e];
            atomicAdd(&hist[de[r] >> 8], 1);
        } else {
            de[r] = -1; se[r] = 0;
        }
    }
    __syncthreads();

    // two-level inclusive scan of hist over 1024 threads
    int v = (tid < NBUCK) ? hist[tid] : 0;
    #pragma unroll
    for (int o = 1; o < 64; o <<= 1) {
        int u = __shfl_up(v, o, 64);
        if (lane >= o) v += u;
    }
    if (lane == 63) wsum[wv] = v;
    __syncthreads();
    if (tid < 16) {
        int s = wsum[tid];
        #pragma unroll
        for (int o = 1; o < 16; o <<= 1) {
            int u = __shfl_up(s, o, 64);
            if (tid >= o) s += u;
        }
        wsum[tid] = s;
    }
    __syncthreads();
    if (wv > 0) v += wsum[wv - 1];
    if (tid < NBUCK) {
        int excl = v - hist[tid];
        roffs[tid] = excl;
        curs[tid]  = excl;
        if (hist[tid] > 0)    // one global atomic per (block,bucket) run
            bbase[tid] = tid * BCAP + atomicAdd(&balloc[tid], hist[tid]);
    }
    __syncthreads();

    // LDS scatter: sort this chunk's edges by bucket
    #pragma unroll
    for (int r = 0; r < 8; ++r) {
        if (de[r] >= 0) {
            int bk  = de[r] >> 8;
            int pos = atomicAdd(&curs[bk], 1);
            stage[pos]  = ((unsigned)(de[r] & 255) << 17) | (unsigned)se[r];
            bstage[pos] = (unsigned short)bk;
        }
    }
    __syncthreads();

    // coalesced run write-out: consecutive e -> consecutive addr within a run
    for (int e = tid; e < m; e += 1024) {
        int bk = bstage[e];
        pairs[bbase[bk] + (e - roffs[bk])] = stage[e];
    }
}

// ---------- K2: per-bucket counting sort (contiguous input, in-place output) ----------
__global__ __launch_bounds__(512) void bucket_sort_kernel(
        unsigned int* __restrict__ pairs,      // in: pairs, out: eidx (aliased)
        const int* __restrict__ balloc,
        int* __restrict__ nbeg, int* __restrict__ nend) {
    __shared__ int hist[256];
    __shared__ int roffs[256];
    __shared__ int curs[256];
    __shared__ int wsum[8];
    __shared__ int sorted[BCAP];    // 20 KB

    int tid   = threadIdx.x;
    int b     = blockIdx.x;
    int lane  = tid & 63;
    int wv    = tid >> 6;
    int node0 = b << 8;
    int nn    = min(256, N_NODES - node0);
    int E     = balloc[b];
    int base  = b * BCAP;

    for (int k = tid; k < 256; k += 512) hist[k] = 0;
    __syncthreads();
    for (int i = tid; i < E; i += 512)
        atomicAdd(&hist[pairs[base + i] >> 17], 1);
    __syncthreads();

    // scan 256 entries (waves 0..3)
    int c = (tid < 256) ? hist[tid] : 0;
    int v = c;
    #pragma unroll
    for (int o = 1; o < 64; o <<= 1) {
        int u = __shfl_up(v, o, 64);
        if (lane >= o) v += u;
    }
    if (tid < 256 && lane == 63) wsum[wv] = v;
    __syncthreads();
    if (tid < 4) {
        int s = wsum[tid];
        int u = __shfl_up(s, 1, 64); if (tid >= 1) s += u;
        u     = __shfl_up(s, 2, 64); if (tid >= 2) s += u;
        wsum[tid] = s;
    }
    __syncthreads();
    if (tid < 256) {
        if (wv > 0) v += wsum[wv - 1];
        int excl = v - c;
        roffs[tid] = excl;
        curs[tid]  = excl;
        if (tid < nn) {
            nbeg[node0 + tid] = base + excl;
            nend[node0 + tid] = base + excl + c;
        }
    }
    __syncthreads();

    // sort into LDS (all reads of pairs for this block finish here)
    for (int i = tid; i < E; i += 512) {
        unsigned int p = pairs[base + i];
        int pos = atomicAdd(&curs[p >> 17], 1);
        sorted[pos] = (int)(p & 0x1FFFFu);
    }
    __syncthreads();
    // in-place rewrite as eidx (coalesced)
    for (int i = tid; i < E; i += 512)
        pairs[base + i] = (unsigned int)sorted[i];
}

// ---------- K3: fused gather(bf16)+transform+pool (R0-proven body, untouched) ----------
#define NODES_PER_WAVE 25
#define GT_NWAVES  (N_NODES / NODES_PER_WAVE)   // 4000
#define GT_BLOCKS  (GT_NWAVES / 4)              // 1000

__device__ __forceinline__ float bfl(unsigned int u) { return __uint_as_float(u << 16); }
__device__ __forceinline__ float bfh(unsigned int u) { return __uint_as_float(u & 0xFFFF0000u); }

__global__ __launch_bounds__(256) void gather_pool_kernel(
        const unsigned short* __restrict__ xh,
        const int*   __restrict__ nbeg,
        const int*   __restrict__ nend,
        const int*   __restrict__ eidx,
        const int*   __restrict__ batch,
        const float* __restrict__ Wg,   // [64,64] (k, f)
        const float* __restrict__ bg,
        const float* __restrict__ Wa,
        const float* __restrict__ ba,
        float*       __restrict__ out_acc,   // [N_GRAPHS, F]
        float*       __restrict__ denom) {  // [N_GRAPHS]
    int tid  = threadIdx.x;
    int lane = tid & 63;
    int grp  = lane >> 3;   // 0..7: row within an 8-row gather batch
    int c    = lane & 7;    // 16-B chunk (8 bf16) within a row
    int waveId = blockIdx.x * 4 + (tid >> 6);

    int n0   = waveId * NODES_PER_WAVE;     // grid exactly covers N_NODES
    int nEnd = n0 + NODES_PER_WAVE;

    float wcol[F];
    #pragma unroll
    for (int k = 0; k < F; ++k) wcol[k] = Wg[k * F + lane];
    float bgl = bg[lane];
    float wal = Wa[lane];
    float ba0 = ba[0];

    const uint4* xh4 = (const uint4*)xh;     // row = 8 uint4

    int   cur_g = batch[n0];
    float accw  = 0.f;   // per-lane: sum e * h[lane]
    float denw  = 0.f;   // replicated: sum e

    // prefetch state: first-chunk edge indices of the current node
    int pb = nbeg[n0];
    int pe = nend[n0];
    int sl_cur = (pb + lane < pe) ? eidx[pb + lane] : 0;

    for (int n = n0; n < nEnd; ++n) {
        int start = pb, end = pe;
        int sl    = sl_cur;
        if (n + 1 < nEnd) {     // prefetch node n+1 while n's gathers fly
            pb = nbeg[n + 1];
            pe = nend[n + 1];
            sl_cur = (pb + lane < pe) ? eidx[pb + lane] : 0;
        }

        float a0=0.f,a1=0.f,a2=0.f,a3=0.f,a4=0.f,a5=0.f,a6=0.f,a7=0.f;
        // first (almost always only) 64-edge chunk
        {
            int jmax = end - start; if (jmax > 64) jmax = 64;
            for (int j = 0; j < jmax; j += 8) {
                int el = j + grp;
                int s  = __shfl(sl, el, 64);
                if (el < jmax) {
                    uint4 v = xh4[s * 8 + c];   // 16 B/lane, 8 rows per instruction
                    a0 += bfl(v.x); a1 += bfh(v.x);
                    a2 += bfl(v.y); a3 += bfh(v.y);
                    a4 += bfl(v.z); a5 += bfh(v.z);
                    a6 += bfl(v.w); a7 += bfh(v.w);
                }
            }
        }
        // rare extra chunks (deg > 64)
        for (int base = start + 64; base < end; base += 64) {
            int jmax = end - base; if (jmax > 64) jmax = 64;
            int sl2 = (base + lane < end) ? eidx[base + lane] : 0;
            for (int j = 0; j < jmax; j += 8) {
                int el = j + grp;
                int s  = __shfl(sl2, el, 64);
                if (el < jmax) {
                    uint4 v = xh4[s * 8 + c];
                    a0 += bfl(v.x); a1 += bfh(v.x);
                    a2 += bfl(v.y); a3 += bfh(v.y);
                    a4 += bfl(v.z); a5 += bfh(v.z);
                    a6 += bfl(v.w); a7 += bfh(v.w);
                }
            }
        }
        #pragma unroll
        for (int o = 8; o <= 32; o <<= 1) {
            a0 += __shfl_xor(a0, o, 64); a1 += __shfl_xor(a1, o, 64);
            a2 += __shfl_xor(a2, o, 64); a3 += __shfl_xor(a3, o, 64);
            a4 += __shfl_xor(a4, o, 64); a5 += __shfl_xor(a5, o, 64);
            a6 += __shfl_xor(a6, o, 64); a7 += __shfl_xor(a7, o, 64);
        }
        {
            uint4 v = xh4[n * 8 + c];   // self row
            a0 += bfl(v.x); a1 += bfh(v.x);
            a2 += bfl(v.y); a3 += bfh(v.y);
            a4 += bfl(v.z); a5 += bfh(v.z);
            a6 += bfl(v.w); a7 += bfh(v.w);
        }

        float re[8] = {a0,a1,a2,a3,a4,a5,a6,a7};
        float q0=0.f,q1=0.f,q2=0.f,q3=0.f,q4=0.f,q5=0.f,q6=0.f,q7=0.f;
        #pragma unroll
        for (int k = 0; k < F; k += 8) {
            int ln = k >> 3;
            q0 += __int_as_float(__builtin_amdgcn_readlane(__float_as_int(re[0]), ln)) * wcol[k + 0];
            q1 += __int_as_float(__builtin_amdgcn_readlane(__float_as_int(re[1]), ln)) * wcol[k + 1];
            q2 += __int_as_float(__builtin_amdgcn_readlane(__float_as_int(re[2]), ln)) * wcol[k + 2];
            q3 += __int_as_float(__builtin_amdgcn_readlane(__float_as_int(re[3]), ln)) * wcol[k + 3];
            q4 += __int_as_float(__builtin_amdgcn_readlane(__float_as_int(re[4]), ln)) * wcol[k + 4];
            q5 += __int_as_float(__builtin_amdgcn_readlane(__float_as_int(re[5]), ln)) * wcol[k + 5];
            q6 += __int_as_float(__builtin_amdgcn_readlane(__float_as_int(re[6]), ln)) * wcol[k + 6];
            q7 += __int_as_float(__builtin_amdgcn_readlane(__float_as_int(re[7]), ln)) * wcol[k + 7];
        }
        float hv = ((q0 + q1) + (q2 + q3)) + ((q4 + q5) + (q6 + q7)) + bgl;
        hv = hv > 0.f ? hv : 0.f;

        float p = hv * wal;
        #pragma unroll
        for (int o = 32; o > 0; o >>= 1)
            p += __shfl_down(p, o, 64);
        float s = __int_as_float(__builtin_amdgcn_readlane(__float_as_int(p), 0)) + ba0;
        float e = __expf(s);    // unshifted: softmax ratio is shift-invariant

        int g = batch[n];       // wave-uniform
        if (g != cur_g) {
            atomicAdd(&out_acc[cur_g * F + lane], accw);
            if (lane == 0) atomicAdd(&denom[cur_g], denw);
            accw = 0.f; denw = 0.f; cur_g = g;
        }
        accw += e * hv;
        denw += e;
    }
    atomicAdd(&out_acc[cur_g * F + lane], accw);
    if (lane == 0) atomicAdd(&denom[cur_g], denw);
}

// ---------- K4: out /= denom ----------
__global__ __launch_bounds__(256) void finalize_kernel(
        float* __restrict__ out, const float* __restrict__ denom) {
    int i = blockIdx.x * 256 + threadIdx.x;
    if (i >= N_GRAPHS * F) return;
    float d = denom[i >> 6];
    out[i] = (d > 0.f) ? out[i] / d : 0.f;
}

extern "C" void kernel_launch(void* const* d_in, const int* in_sizes, int n_in,
                              void* d_out, int out_size, void* d_ws, size_t ws_size,
                              hipStream_t stream) {
    const float* x     = (const float*)d_in[0];
    const int*   ei    = (const int*)d_in[1];   // [2, N_EDGES]
    const int*   batch = (const int*)d_in[2];   // [N_NODES]
    const float* Wg    = (const float*)d_in[3];
    const float* bg    = (const float*)d_in[4];
    const float* Wa    = (const float*)d_in[5];
    const float* ba    = (const float*)d_in[6];
    float* out = (float*)d_out;

    const int* src = ei;
    const int* dst = ei + N_EDGES;

    // workspace layout (bytes)
    char* ws = (char*)d_ws;
    unsigned short* xh     = (unsigned short*)(ws);            // 12,800,000
    unsigned int*   pairs  = (unsigned int*)(ws + 12800000);   //  8,007,680 (NBUCK*BCAP*4; doubles as eidx)
    int*            nbeg   = (int*)(ws + 20807680);            //    400,000
    int*            nend   = (int*)(ws + 21207808);            //    400,000
    int*            balloc = (int*)(ws + 21607936);            //      2,048
    float*          denom  = (float*)(ws + 21610240);          //      1,024

    zero_kernel       <<<64, 256, 0, stream>>>(balloc, out, denom);
    bin_cast_kernel   <<<BC_BLOCKS, 1024, 0, stream>>>(src, dst, x, xh, pairs, balloc);
    bucket_sort_kernel<<<NBUCK, 512, 0, stream>>>(pairs, balloc, nbeg, nend);
    gather_pool_kernel<<<GT_BLOCKS, 256, 0, stream>>>(
        xh, nbeg, nend, (const int*)pairs, batch, Wg, bg, Wa, ba, out, denom);
    finalize_kernel   <<<(N_GRAPHS * F + 255) / 256, 256, 0, stream>>>(out, denom);
}